// Round 8
// baseline (184.456 us; speedup 1.0000x reference)
//
#include <hip/hip_runtime.h>
#include <math.h>

#define N_RAYS 65536
#define LAMBDA_OPACITY 0.001f
#define LAMBDA_DISTORTION 0.001f

#define RAYS_PER_BLOCK 64     // 4 waves x 16 rays
#define RAYS_PER_WAVE 16      // 3072 samples = 768 quads = 12 iterations

// ---------------------------------------------------------------------------
// DPP wave64 inclusive-add scan (canonical gfx9 sequence, all-VALU) —
// verified R5/R7.
// ---------------------------------------------------------------------------
template <int CTRL, int ROW_MASK>
__device__ __forceinline__ float dpp_add(float x) {
    int s = __builtin_amdgcn_update_dpp(0, __float_as_int(x),
                                        CTRL, ROW_MASK, 0xf, false);
    return x + __int_as_float(s);
}

__device__ __forceinline__ float wave64_incl_scan(float x) {
    x = dpp_add<0x111, 0xf>(x);  // row_shr:1
    x = dpp_add<0x112, 0xf>(x);  // row_shr:2
    x = dpp_add<0x114, 0xf>(x);  // row_shr:4
    x = dpp_add<0x118, 0xf>(x);  // row_shr:8
    x = dpp_add<0x142, 0xa>(x);  // row_bcast:15 -> rows 1,3
    x = dpp_add<0x143, 0xc>(x);  // row_bcast:31 -> rows 2,3
    return x;
}

// ---------------------------------------------------------------------------
// Distortion, copy-shaped: block owns 64 consecutive rays (48KB/array
// contiguous); wave owns 16 rays = 12 iterations of 3 contiguous dwordx4
// loads (36 independent loads/wave -> deep MLP, long sequential streams).
// Under the identity layout (start=192*ray, count=192), ray boundaries fall
// at STATIC lanes per iteration (period 3: B=48,32,16), so the segmented
// scan uses compile-time boundaries. Generic per-ray fallback otherwise.
// ---------------------------------------------------------------------------
__global__ __launch_bounds__(256)
void distortion_kernel(
    const float* __restrict__ ws,
    const float* __restrict__ deltas,
    const float* __restrict__ ts,
    const int*   __restrict__ rays_a,
    float* __restrict__ out)
{
    const int lane = threadIdx.x & 63;
    const int wave = threadIdx.x >> 6;
    const int rblk = blockIdx.x * RAYS_PER_BLOCK;

    // --- block-wide identity-layout check ---
    __shared__ int ok_s;
    if (threadIdx.x == 0) ok_s = 1;
    __syncthreads();
    if (threadIdx.x < RAYS_PER_BLOCK) {
        const int r  = rblk + threadIdx.x;
        const int st = rays_a[3 * r + 1];
        const int ct = rays_a[3 * r + 2];
        if (st != 192 * r || ct != 192) ok_s = 0;
    }
    __syncthreads();
    const bool ok = (ok_s != 0);

    const int ray0 = rblk + wave * RAYS_PER_WAVE;

    if (ok) {
        const float4* wp4 = (const float4*)(ws     + 192 * ray0);
        const float4* tp4 = (const float4*)(ts     + 192 * ray0);
        const float4* dp4 = (const float4*)(deltas + 192 * ray0);

        // lanes 0..15 hold out-ray indices of the wave's 16 rays
        int my_or = 0;
        if (lane < RAYS_PER_WAVE) my_or = rays_a[3 * (ray0 + lane) + 0];

        float carry_w = 0.f, carry_wt = 0.f, carry_acc = 0.f;

        #pragma unroll
        for (int i = 0; i < 12; ++i) {
            const int m    = i % 3;
            const int B    = (m == 0) ? 48 : (m == 1) ? 32 : 16;  // boundary lane
            const int Lray = (4 * i) / 3;                          // left ray id

            const int q = 64 * i + lane;
            const float4 vw = wp4[q];
            const float4 vt = tp4[q];
            const float4 vd = dp4[q];

            const float w0 = vw.x, w1 = vw.y, w2 = vw.z, w3 = vw.w;
            const float t0 = vt.x, t1 = vt.y, t2 = vt.z, t3 = vt.w;

            const float lw  = (w0 + w1) + (w2 + w3);
            const float lwt = (w0 * t0 + w1 * t1) + (w2 * t2 + w3 * t3);

            const float Iw  = wave64_incl_scan(lw);
            const float Iwt = wave64_incl_scan(lwt);

            const float Pw  = __shfl(Iw,  B - 1);
            const float Pwt = __shfl(Iwt, B - 1);

            const bool right = (lane >= B);
            float e_w  = (Iw  - lw ) + (right ? -Pw  : carry_w);
            float e_wt = (Iwt - lwt) + (right ? -Pwt : carry_wt);

            float acc = 0.f;
            acc += 2.f * w0 * (t0 * e_w - e_wt) + w0 * w0 * vd.x * (1.f / 3.f);
            e_w += w0; e_wt += w0 * t0;
            acc += 2.f * w1 * (t1 * e_w - e_wt) + w1 * w1 * vd.y * (1.f / 3.f);
            e_w += w1; e_wt += w1 * t1;
            acc += 2.f * w2 * (t2 * e_w - e_wt) + w2 * w2 * vd.z * (1.f / 3.f);
            e_w += w2; e_wt += w2 * t2;
            acc += 2.f * w3 * (t3 * e_w - e_wt) + w3 * w3 * vd.w * (1.f / 3.f);

            const float Iacc = wave64_incl_scan(acc);
            const float Pacc = __shfl(Iacc, B - 1);

            // left segment closes ray Lray at lane B-1
            const int lor = __shfl(my_or, Lray);
            if (lane == B - 1)
                out[3 * N_RAYS + lor] = LAMBDA_DISTORTION * (carry_acc + Iacc);

            if (m == 2) {
                // right segment closes ray Lray+1 entirely within this iter
                const int ror = __shfl(my_or, Lray + 1);
                if (lane == 63)
                    out[3 * N_RAYS + ror] = LAMBDA_DISTORTION * (Iacc - Pacc);
                carry_w = 0.f; carry_wt = 0.f; carry_acc = 0.f;
            } else {
                // right segment opens ray Lray+1; carry its partial sums
                const float Tw   = __shfl(Iw,   63);
                const float Twt  = __shfl(Iwt,  63);
                const float Tacc = __shfl(Iacc, 63);
                carry_w   = Tw   - Pw;
                carry_wt  = Twt  - Pwt;
                carry_acc = Tacc - Pacc;
            }
        }
    } else {
        // generic fallback: per-ray, chunks of 256 samples with carries
        for (int r = ray0; r < ray0 + RAYS_PER_WAVE; ++r) {
            const int orv = rays_a[3 * r + 0];
            const int st  = rays_a[3 * r + 1];
            const int ct  = rays_a[3 * r + 2];

            float c_w = 0.f, c_wt = 0.f, racc = 0.f;
            for (int base = 0; base < ct; base += 256) {
                float w[4], t[4], d[4];
                #pragma unroll
                for (int e = 0; e < 4; ++e) {
                    const int p  = base + 4 * lane + e;
                    const bool okp = p < ct;
                    w[e] = okp ? ws[st + p]     : 0.f;
                    t[e] = okp ? ts[st + p]     : 0.f;
                    d[e] = okp ? deltas[st + p] : 0.f;
                }
                const float lw  = (w[0] + w[1]) + (w[2] + w[3]);
                const float lwt = (w[0]*t[0] + w[1]*t[1]) + (w[2]*t[2] + w[3]*t[3]);
                const float Iw  = wave64_incl_scan(lw);
                const float Iwt = wave64_incl_scan(lwt);

                float e_w  = c_w  + Iw  - lw;
                float e_wt = c_wt + Iwt - lwt;

                float acc = 0.f;
                #pragma unroll
                for (int e = 0; e < 4; ++e) {
                    acc += 2.f * w[e] * (t[e] * e_w - e_wt) + w[e] * w[e] * d[e] * (1.f / 3.f);
                    e_w  += w[e];
                    e_wt += w[e] * t[e];
                }
                const float Iacc = wave64_incl_scan(acc);
                racc += __shfl(Iacc, 63);
                c_w  += __shfl(Iw,  63);
                c_wt += __shfl(Iwt, 63);
            }
            if (lane == 63)
                out[3 * N_RAYS + orv] = LAMBDA_DISTORTION * racc;
        }
    }
}

// ---------------------------------------------------------------------------
// Per-ray cheap terms: 1 thread per ray, fully coalesced (~6 MB total).
// ---------------------------------------------------------------------------
__global__ __launch_bounds__(256)
void perray_kernel(
    const float* __restrict__ rgb_coarse,
    const float* __restrict__ rgb_fine,
    const float* __restrict__ rgb_target,
    const float* __restrict__ depth,
    const float* __restrict__ depth_target,
    const float* __restrict__ opacity,
    float* __restrict__ out)
{
    const int r = blockIdx.x * blockDim.x + threadIdx.x;
    if (r >= N_RAYS) return;

    const float rt0 = rgb_target[r * 3 + 0];
    const float rt1 = rgb_target[r * 3 + 1];
    const float rt2 = rgb_target[r * 3 + 2];
    const float c0 = rgb_coarse[r * 3 + 0] - rt0;
    const float c1 = rgb_coarse[r * 3 + 1] - rt1;
    const float c2 = rgb_coarse[r * 3 + 2] - rt2;
    const float f0 = rgb_fine[r * 3 + 0] - rt0;
    const float f1 = rgb_fine[r * 3 + 1] - rt1;
    const float f2 = rgb_fine[r * 3 + 2] - rt2;

    out[r] = (c0 * c0 + c1 * c1 + c2 * c2) * (1.f / 3.f)
           + (f0 * f0 + f1 * f1 + f2 * f2) * (1.f / 3.f);

    out[N_RAYS + r] = fabsf(depth[r] - depth_target[r]);

    const float o = opacity[r] + 1e-10f;
    out[2 * N_RAYS + r] = LAMBDA_OPACITY * (-o * logf(o));
}

extern "C" void kernel_launch(void* const* d_in, const int* in_sizes, int n_in,
                              void* d_out, int out_size, void* d_ws, size_t ws_size,
                              hipStream_t stream) {
    const float* rgb_coarse   = (const float*)d_in[0];
    const float* rgb_fine     = (const float*)d_in[1];
    const float* rgb_target   = (const float*)d_in[2];
    const float* depth        = (const float*)d_in[3];
    const float* depth_target = (const float*)d_in[4];
    const float* opacity      = (const float*)d_in[5];
    const float* ws           = (const float*)d_in[6];
    const float* deltas       = (const float*)d_in[7];
    const float* ts           = (const float*)d_in[8];
    const int*   rays_a       = (const int*)d_in[9];
    float* out = (float*)d_out;

    distortion_kernel<<<N_RAYS / RAYS_PER_BLOCK, 256, 0, stream>>>(
        ws, deltas, ts, rays_a, out);

    perray_kernel<<<N_RAYS / 256, 256, 0, stream>>>(
        rgb_coarse, rgb_fine, rgb_target, depth, depth_target, opacity, out);
}

// Round 10
// 168.696 us; speedup vs baseline: 1.0934x; 1.0934x over previous
//
#include <hip/hip_runtime.h>
#include <math.h>

#define N_RAYS 65536
#define LAMBDA_OPACITY 0.001f
#define LAMBDA_DISTORTION 0.001f

// native clang vector type — accepted by __builtin_nontemporal_load
typedef float f32x4 __attribute__((ext_vector_type(4)));

// ---------------------------------------------------------------------------
// DPP wave64 inclusive-add scan (canonical gfx9 sequence, all-VALU) —
// verified R5/R7.
// ---------------------------------------------------------------------------
template <int CTRL, int ROW_MASK>
__device__ __forceinline__ float dpp_add(float x) {
    int s = __builtin_amdgcn_update_dpp(0, __float_as_int(x),
                                        CTRL, ROW_MASK, 0xf, false);
    return x + __int_as_float(s);
}

__device__ __forceinline__ float wave64_incl_scan(float x) {
    x = dpp_add<0x111, 0xf>(x);  // row_shr:1
    x = dpp_add<0x112, 0xf>(x);  // row_shr:2
    x = dpp_add<0x114, 0xf>(x);  // row_shr:4
    x = dpp_add<0x118, 0xf>(x);  // row_shr:8
    x = dpp_add<0x142, 0xa>(x);  // row_bcast:15 -> rows 1,3
    x = dpp_add<0x143, 0xc>(x);  // row_bcast:31 -> rows 2,3
    return x;
}

// ---------------------------------------------------------------------------
// Distortion: R7 structure (one wave per ray, speculative identity-layout
// loads concurrent with the meta load). R10 change: the three 768B data
// loads are NONTEMPORAL (nt) — no L2/L3 allocation — to A/B the cache path
// against the 52us plateau. Everything else identical to verified R7.
// ---------------------------------------------------------------------------
__global__ __launch_bounds__(256)
void distortion_kernel(
    const float* __restrict__ ws,
    const float* __restrict__ deltas,
    const float* __restrict__ ts,
    const int*   __restrict__ rays_a,
    float* __restrict__ out)
{
    const int lane = threadIdx.x & 63;
    const int ray  = blockIdx.x * 4 + (threadIdx.x >> 6);

    // --- speculative nontemporal data loads (identity layout) ---
    f32x4 vw = {0.f, 0.f, 0.f, 0.f};
    f32x4 vt = {0.f, 0.f, 0.f, 0.f};
    f32x4 vd = {0.f, 0.f, 0.f, 0.f};
    if (lane < 48) {
        const int sp = 192 * ray + 4 * lane;
        vw = __builtin_nontemporal_load((const f32x4*)(ws     + sp));
        vt = __builtin_nontemporal_load((const f32x4*)(ts     + sp));
        vd = __builtin_nontemporal_load((const f32x4*)(deltas + sp));
    }

    // --- meta load, independent of the data loads -> same round trip ---
    const int out_ray = rays_a[ray * 3 + 0];
    const int start   = rays_a[ray * 3 + 1];
    const int count   = rays_a[ray * 3 + 2];

    __builtin_amdgcn_sched_barrier(0);

    float w[4] = {0.f, 0.f, 0.f, 0.f};
    float t[4] = {0.f, 0.f, 0.f, 0.f};
    float d[4] = {0.f, 0.f, 0.f, 0.f};

    if (start == 192 * ray && count == 192) {
        if (lane < 48) {
            w[0]=vw.x; w[1]=vw.y; w[2]=vw.z; w[3]=vw.w;
            t[0]=vt.x; t[1]=vt.y; t[2]=vt.z; t[3]=vt.w;
            d[0]=vd.x; d[1]=vd.y; d[2]=vd.z; d[3]=vd.w;
        }
    } else {
        // generic fallback: any start/count, guarded scalar loads
        #pragma unroll
        for (int e = 0; e < 4; ++e) {
            const int p  = 4 * lane + e;
            const bool ok = p < count;
            w[e] = ok ? ws[start + p]     : 0.f;
            t[e] = ok ? ts[start + p]     : 0.f;
            d[e] = ok ? deltas[start + p] : 0.f;
        }
    }

    // --- per-lane quad totals ---
    const float wt0 = w[0] * t[0], wt1 = w[1] * t[1];
    const float wt2 = w[2] * t[2], wt3 = w[3] * t[3];
    const float lw  = (w[0] + w[1]) + (w[2] + w[3]);
    const float lwt = (wt0 + wt1) + (wt2 + wt3);

    // --- DPP inclusive scans over quad totals (two independent chains) ---
    const float iw  = wave64_incl_scan(lw);
    const float iwt = wave64_incl_scan(lwt);

    // exclusive base for this quad
    float e_w  = iw  - lw;
    float e_wt = iwt - lwt;

    // lane-local sequential exclusive accumulation over the 4 samples
    float acc = 0.f;
    #pragma unroll
    for (int e = 0; e < 4; ++e) {
        acc += 2.f * w[e] * (t[e] * e_w - e_wt) + w[e] * w[e] * d[e] * (1.f / 3.f);
        e_w  += w[e];
        e_wt += w[e] * t[e];
    }

    // ray total via one more DPP scan; lane 63 holds the full sum
    const float tot = wave64_incl_scan(acc);
    if (lane == 63)
        out[3 * N_RAYS + out_ray] = LAMBDA_DISTORTION * tot;
}

// ---------------------------------------------------------------------------
// Per-ray cheap terms: 1 thread per ray, fully coalesced (~6 MB total).
// ---------------------------------------------------------------------------
__global__ __launch_bounds__(256)
void perray_kernel(
    const float* __restrict__ rgb_coarse,
    const float* __restrict__ rgb_fine,
    const float* __restrict__ rgb_target,
    const float* __restrict__ depth,
    const float* __restrict__ depth_target,
    const float* __restrict__ opacity,
    float* __restrict__ out)
{
    const int r = blockIdx.x * blockDim.x + threadIdx.x;
    if (r >= N_RAYS) return;

    const float rt0 = rgb_target[r * 3 + 0];
    const float rt1 = rgb_target[r * 3 + 1];
    const float rt2 = rgb_target[r * 3 + 2];
    const float c0 = rgb_coarse[r * 3 + 0] - rt0;
    const float c1 = rgb_coarse[r * 3 + 1] - rt1;
    const float c2 = rgb_coarse[r * 3 + 2] - rt2;
    const float f0 = rgb_fine[r * 3 + 0] - rt0;
    const float f1 = rgb_fine[r * 3 + 1] - rt1;
    const float f2 = rgb_fine[r * 3 + 2] - rt2;

    out[r] = (c0 * c0 + c1 * c1 + c2 * c2) * (1.f / 3.f)
           + (f0 * f0 + f1 * f1 + f2 * f2) * (1.f / 3.f);

    out[N_RAYS + r] = fabsf(depth[r] - depth_target[r]);

    const float o = opacity[r] + 1e-10f;
    out[2 * N_RAYS + r] = LAMBDA_OPACITY * (-o * logf(o));
}

extern "C" void kernel_launch(void* const* d_in, const int* in_sizes, int n_in,
                              void* d_out, int out_size, void* d_ws, size_t ws_size,
                              hipStream_t stream) {
    const float* rgb_coarse   = (const float*)d_in[0];
    const float* rgb_fine     = (const float*)d_in[1];
    const float* rgb_target   = (const float*)d_in[2];
    const float* depth        = (const float*)d_in[3];
    const float* depth_target = (const float*)d_in[4];
    const float* opacity      = (const float*)d_in[5];
    const float* ws           = (const float*)d_in[6];
    const float* deltas       = (const float*)d_in[7];
    const float* ts           = (const float*)d_in[8];
    const int*   rays_a       = (const int*)d_in[9];
    float* out = (float*)d_out;

    // 4 waves per block, 1 ray per wave (R5/R7 grid shape)
    distortion_kernel<<<N_RAYS / 4, 256, 0, stream>>>(
        ws, deltas, ts, rays_a, out);

    perray_kernel<<<N_RAYS / 256, 256, 0, stream>>>(
        rgb_coarse, rgb_fine, rgb_target, depth, depth_target, opacity, out);
}